// Round 4
// baseline (532.356 us; speedup 1.0000x reference)
//
#include <hip/hip_runtime.h>
#include <hip/hip_bf16.h>

typedef __bf16 bf16_t;
typedef __attribute__((ext_vector_type(8))) __bf16 bf16x8;
typedef __attribute__((ext_vector_type(4))) __bf16 bf16x4;
typedef __attribute__((ext_vector_type(4))) float f32x4;

#define MFMA16(A, B, C) __builtin_amdgcn_mfma_f32_16x16x32_bf16((A), (B), (C), 0, 0, 0)

#if __has_builtin(__builtin_amdgcn_exp2f)
#define EXP2F(x) __builtin_amdgcn_exp2f(x)
#else
#define EXP2F(x) exp2f(x)
#endif

// log2(e)/8 : folded into the Q plane in gemm_qkv's fp32 epilogue
#define QSCALE 0.1803368801111244f

// ------------------------------------------------------------- weights cvt
__global__ __launch_bounds__(256) void cvt_kernel(const float* __restrict__ Wq,
                                                  const float* __restrict__ Wp,
                                                  bf16_t* __restrict__ qh,
                                                  bf16_t* __restrict__ ql,
                                                  bf16_t* __restrict__ ph,
                                                  bf16_t* __restrict__ pl) {
  const int i = (blockIdx.x * 256 + threadIdx.x) * 4;
  if (i < 786432) {
    const float4 v = *(const float4*)(Wq + i);
    const float vv[4] = {v.x, v.y, v.z, v.w};
    bf16x4 h, l;
    #pragma unroll
    for (int j = 0; j < 4; ++j) {
      h[j] = (bf16_t)vv[j];
      l[j] = (bf16_t)(vv[j] - (float)h[j]);
    }
    *(bf16x4*)(qh + i) = h;
    *(bf16x4*)(ql + i) = l;
  } else {
    const int j0 = i - 786432;
    const float4 v = *(const float4*)(Wp + j0);
    const float vv[4] = {v.x, v.y, v.z, v.w};
    bf16x4 h, l;
    #pragma unroll
    for (int j = 0; j < 4; ++j) {
      h[j] = (bf16_t)vv[j];
      l[j] = (bf16_t)(vv[j] - (float)h[j]);
    }
    *(bf16x4*)(ph + j0) = h;
    *(bf16x4*)(pl + j0) = l;
  }
}

// ------------------------------------------------------------- LayerNorm
__global__ __launch_bounds__(256) void ln_kernel(const float* __restrict__ X,
                                                 const float* __restrict__ gamma,
                                                 const float* __restrict__ beta,
                                                 bf16_t* __restrict__ Th,
                                                 bf16_t* __restrict__ Tl) {
  __shared__ __align__(16) bf16_t tile[512 * 32];  // [c][pi]
  __shared__ float red1[8][32];
  __shared__ float red2[8][32];
  __shared__ float smu[32], srs[32];
  __shared__ float sg[512], sb[512];
  const int tid = threadIdx.x;
  const int g = tid >> 5, pi = tid & 31;
  const int b = blockIdx.y;
  const int p0 = blockIdx.x * 32;
  sg[tid] = gamma[tid];
  sg[tid + 256] = gamma[tid + 256];
  sb[tid] = beta[tid];
  sb[tid + 256] = beta[tid + 256];
  const float* Xb = X + ((size_t)b * 512) * 4096 + p0;
  float s1 = 0.f, s2 = 0.f;
  #pragma unroll 4
  for (int c = g * 64; c < g * 64 + 64; ++c) {
    const float x = Xb[(size_t)c * 4096 + pi];
    tile[c * 32 + pi] = (bf16_t)x;
    s1 += x;
    s2 += x * x;
  }
  red1[g][pi] = s1;
  red2[g][pi] = s2;
  __syncthreads();
  if (tid < 32) {
    float a = 0.f, q = 0.f;
    #pragma unroll
    for (int k = 0; k < 8; ++k) {
      a += red1[k][tid];
      q += red2[k][tid];
    }
    const float mu = a * (1.f / 512.f);
    const float var = q * (1.f / 512.f) - mu * mu;
    smu[tid] = mu;
    srs[tid] = rsqrtf(var + 1e-5f);
  }
  __syncthreads();
  const int pi2 = tid >> 3, qq = tid & 7;
  const float mu = smu[pi2], rs = srs[pi2];
  const size_t outoff = ((size_t)(b * 4096 + p0 + pi2)) * 512;
  #pragma unroll
  for (int ii = 0; ii < 8; ++ii) {
    const int c0 = qq * 64 + ii * 8;
    bf16x8 ph, pl;
    #pragma unroll
    for (int j = 0; j < 8; ++j) {
      const float x = (float)tile[(c0 + j) * 32 + pi2];
      const float y = (x - mu) * rs * sg[c0 + j] + sb[c0 + j];
      const bf16_t hi = (bf16_t)y;
      ph[j] = hi;
      pl[j] = (bf16_t)(y - (float)hi);
    }
    *(bf16x8*)(Th + outoff + c0) = ph;
    *(bf16x8*)(Tl + outoff + c0) = pl;
  }
}

// ------------------------------------------------------------- QKV GEMM
// global_load_lds staging (pre-swizzled source), 3-term hi/lo split.
// Q-region outputs pre-scaled by log2(e)/8 in fp32 (exact for attn's exp2).
__global__ __launch_bounds__(256) void gemm_qkv(const bf16_t* __restrict__ Wqh,
                                                const bf16_t* __restrict__ Wql,
                                                const bf16_t* __restrict__ Th,
                                                const bf16_t* __restrict__ Tl,
                                                const float* __restrict__ bqkv,
                                                bf16_t* __restrict__ QKV) {
  extern __shared__ char smem[];
  char* const Ah = smem;
  char* const Al = smem + 16384;
  char* const Bh = smem + 32768;
  char* const Bl = smem + 49152;
  const int pos0 = blockIdx.x * 128;
  const int oc0 = blockIdx.y * 128;
  const int tid = threadIdx.x;
  const int l = tid & 63, w = tid >> 6;
  const int wr = w >> 1, wc = w & 1;
  f32x4 acc[4][4] = {};
  for (int kt = 0; kt < 512; kt += 64) {
    __syncthreads();
    #pragma unroll
    for (int i = 0; i < 4; ++i) {
      const int chunk = tid + 256 * i;
      const int row = chunk >> 3;
      const int cp = (chunk & 7) ^ (row & 7);  // pre-swizzled source
      const size_t offA = (size_t)(oc0 + row) * 512 + kt + cp * 8;
      const size_t offB = (size_t)(pos0 + row) * 512 + kt + cp * 8;
      __builtin_amdgcn_global_load_lds(
          (const __attribute__((address_space(1))) void*)(Wqh + offA),
          (__attribute__((address_space(3))) void*)(Ah + chunk * 16), 16, 0, 0);
      __builtin_amdgcn_global_load_lds(
          (const __attribute__((address_space(1))) void*)(Wql + offA),
          (__attribute__((address_space(3))) void*)(Al + chunk * 16), 16, 0, 0);
      __builtin_amdgcn_global_load_lds(
          (const __attribute__((address_space(1))) void*)(Th + offB),
          (__attribute__((address_space(3))) void*)(Bh + chunk * 16), 16, 0, 0);
      __builtin_amdgcn_global_load_lds(
          (const __attribute__((address_space(1))) void*)(Tl + offB),
          (__attribute__((address_space(3))) void*)(Bl + chunk * 16), 16, 0, 0);
    }
    __syncthreads();
    #pragma unroll
    for (int ks = 0; ks < 2; ++ks) {
      bf16x8 ah[4], al[4], bh[4], bl[4];
      #pragma unroll
      for (int mt = 0; mt < 4; ++mt) {
        const int row = wr * 64 + mt * 16 + (l & 15);
        const int off = row * 128 + ((ks * 64 + (l >> 4) * 16) ^ ((row & 7) << 4));
        ah[mt] = *(const bf16x8*)(Ah + off);
        al[mt] = *(const bf16x8*)(Al + off);
      }
      #pragma unroll
      for (int nt = 0; nt < 4; ++nt) {
        const int row = wc * 64 + nt * 16 + (l & 15);
        const int off = row * 128 + ((ks * 64 + (l >> 4) * 16) ^ ((row & 7) << 4));
        bh[nt] = *(const bf16x8*)(Bh + off);
        bl[nt] = *(const bf16x8*)(Bl + off);
      }
      #pragma unroll
      for (int mt = 0; mt < 4; ++mt)
        #pragma unroll
        for (int nt = 0; nt < 4; ++nt) {
          acc[mt][nt] = MFMA16(ah[mt], bh[nt], acc[mt][nt]);
          acc[mt][nt] = MFMA16(ah[mt], bl[nt], acc[mt][nt]);
          acc[mt][nt] = MFMA16(al[mt], bh[nt], acc[mt][nt]);
        }
    }
  }
  #pragma unroll
  for (int mt = 0; mt < 4; ++mt) {
    const int ocb = oc0 + wr * 64 + mt * 16 + 4 * (l >> 4);
    const float4 bias = *(const float4*)(bqkv + ocb);
    const float qs = ((ocb % 192) < 64) ? QSCALE : 1.0f;
    #pragma unroll
    for (int nt = 0; nt < 4; ++nt) {
      const int pos = pos0 + wc * 64 + nt * 16 + (l & 15);
      bf16x4 o;
      o[0] = (bf16_t)((acc[mt][nt][0] + bias.x) * qs);
      o[1] = (bf16_t)((acc[mt][nt][1] + bias.y) * qs);
      o[2] = (bf16_t)((acc[mt][nt][2] + bias.z) * qs);
      o[3] = (bf16_t)((acc[mt][nt][3] + bias.w) * qs);
      *(bf16x4*)(QKV + (size_t)pos * 1536 + ocb) = o;
    }
  }
}

// ------------------------------------------------------------- attention
// Swapped QK^T, exp2 no-max softmax (Q pre-scaled by log2e/8 upstream),
// denominator via MFMA-with-ones (layout-matched to acc_o), K via
// global_load_lds double-buffer, XOR-swizzled Vt, LDS = 40960 B exactly
// -> 4 blocks/CU.
__global__ __launch_bounds__(256, 4) void attn_kernel(const bf16_t* __restrict__ QKV,
                                                      bf16_t* __restrict__ Oh,
                                                      bf16_t* __restrict__ Ol) {
  const int o = blockIdx.x;
  const int sid = (o & 7) * 128 + (o >> 3);  // 4 (b,h) pairs per XCD
  const int qt = sid & 31;
  const int bh = sid >> 5;
  const int b = bh >> 3, h = bh & 7;
  const int tid = threadIdx.x;
  const int l = tid & 63, w = tid >> 6;
  const int lg = l >> 4, lr = l & 15;

  __shared__ __align__(16) bf16_t KsA[64 * 64];    // [key][d] XOR-swizzled, 8KB
  __shared__ __align__(16) bf16_t KsB[64 * 64];    // 8KB
  __shared__ __align__(16) bf16_t Vt[64 * 64];     // [d][key] XOR-swizzled, 8KB
  __shared__ __align__(16) bf16_t Ps[4][32 * 64];  // per-wave P / O staging, 16KB

  const bf16_t* base = QKV + (size_t)(b * 4096) * 1536 + h * 192;
  const bf16_t* kbase = base + 64;
  const bf16_t* vbase = base + 128;
  const int q0 = qt * 128 + w * 32;

  // Q fragments (already scaled by log2e/8 upstream in fp32)
  bf16x8 qf[2][2];
  #pragma unroll
  for (int mq = 0; mq < 2; ++mq)
    #pragma unroll
    for (int ks = 0; ks < 2; ++ks)
      qf[mq][ks] = *(const bf16x8*)(base + (size_t)(q0 + mq * 16 + lr) * 1536 +
                                    ks * 32 + 8 * lg);

  bf16x8 onesb;
  {
    const bf16_t one = (bf16_t)1.0f;
    #pragma unroll
    for (int j = 0; j < 8; ++j) onesb[j] = one;
  }

  f32x4 acc_o[2][4] = {};
  f32x4 acc_d[2] = {};
  char* const psw = (char*)&Ps[w][0];

  auto stageK = [&](bf16_t* dst, int k0) {
    #pragma unroll
    for (int i = 0; i < 2; ++i) {
      const int c = tid + 256 * i;
      const int row = c >> 3;
      const int cp = (c & 7) ^ (row & 7);  // pre-swizzled source
      const bf16_t* g = kbase + (size_t)(k0 + row) * 1536 + cp * 8;
      __builtin_amdgcn_global_load_lds(
          (const __attribute__((address_space(1))) void*)g,
          (__attribute__((address_space(3))) void*)((char*)dst + c * 16), 16, 0, 0);
    }
  };
  auto loadV = [&](int k0, bf16x8& v0, bf16x8& v1) {
    const bf16_t* vs = vbase + (size_t)(k0 + l) * 1536 + w * 16;
    v0 = *(const bf16x8*)vs;
    v1 = *(const bf16x8*)(vs + 8);
  };
  auto writeV = [&](bf16x8 v0, bf16x8 v1) {
    char* const vt = (char*)Vt;
    #pragma unroll
    for (int j = 0; j < 8; ++j) {
      const int d0 = w * 16 + j, d1 = w * 16 + 8 + j;
      *(bf16_t*)(vt + d0 * 128 + ((2 * l) ^ ((d0 & 7) << 4))) = v0[j];
      *(bf16_t*)(vt + d1 * 128 + ((2 * l) ^ ((d1 & 7) << 4))) = v1[j];
    }
  };
  auto compute = [&](const bf16_t* Kbuf) {
    // S^T = mfma(K, Q): cols = q (lr), rows = key kt*16 + 4*lg + r
    f32x4 st[4][2] = {};
    __builtin_amdgcn_s_setprio(1);
    #pragma unroll
    for (int ks = 0; ks < 2; ++ks) {
      bf16x8 kb[4];
      #pragma unroll
      for (int kt = 0; kt < 4; ++kt) {
        const int row = kt * 16 + lr;
        kb[kt] = *(const bf16x8*)((const char*)Kbuf + row * 128 +
                                  ((ks * 64 + lg * 16) ^ ((row & 7) << 4)));
      }
      #pragma unroll
      for (int kt = 0; kt < 4; ++kt) {
        st[kt][0] = MFMA16(kb[kt], qf[0][ks], st[kt][0]);
        st[kt][1] = MFMA16(kb[kt], qf[1][ks], st[kt][1]);
      }
    }
    __builtin_amdgcn_s_setprio(0);
    // p = exp2(s'), packed bf16 P into per-wave LDS
    #pragma unroll
    for (int mq = 0; mq < 2; ++mq) {
      const int prow = mq * 16 + lr;
      const int rs = (prow & 7) << 4;
      #pragma unroll
      for (int kt = 0; kt < 4; ++kt) {
        bf16x4 pk;
        pk[0] = (bf16_t)EXP2F(st[kt][mq][0]);
        pk[1] = (bf16_t)EXP2F(st[kt][mq][1]);
        pk[2] = (bf16_t)EXP2F(st[kt][mq][2]);
        pk[3] = (bf16_t)EXP2F(st[kt][mq][3]);
        *(bf16x4*)(psw + prow * 128 + ((kt * 32 + lg * 8) ^ rs)) = pk;
      }
    }
    // O += P V ; denom += P * ones (C/D layout matches acc_o rows)
    #pragma unroll
    for (int ks = 0; ks < 2; ++ks) {
      bf16x8 pa[2], vb[4];
      #pragma unroll
      for (int mt = 0; mt < 2; ++mt) {
        const int row = mt * 16 + lr;
        pa[mt] = *(const bf16x8*)(psw + row * 128 +
                                  ((ks * 64 + lg * 16) ^ ((row & 7) << 4)));
      }
      #pragma unroll
      for (int dt = 0; dt < 4; ++dt) {
        const int row = dt * 16 + lr;
        vb[dt] = *(const bf16x8*)((const char*)Vt + row * 128 +
                                  ((ks * 64 + lg * 16) ^ ((row & 7) << 4)));
      }
      __builtin_amdgcn_s_setprio(1);
      #pragma unroll
      for (int mt = 0; mt < 2; ++mt) {
        #pragma unroll
        for (int dt = 0; dt < 4; ++dt)
          acc_o[mt][dt] = MFMA16(pa[mt], vb[dt], acc_o[mt][dt]);
        acc_d[mt] = MFMA16(pa[mt], onesb, acc_d[mt]);
      }
      __builtin_amdgcn_s_setprio(0);
    }
  };

  // prologue
  stageK(KsA, 0);
  bf16x8 va0, va1, vb0, vb1;
  loadV(0, va0, va1);

  for (int t = 0; t < 64; t += 2) {
    __syncthreads();
    writeV(va0, va1);
    __syncthreads();  // publish KsA(t) + Vt(t)
    stageK(KsB, (t + 1) * 64);
    loadV((t + 1) * 64, vb0, vb1);
    compute(KsA);

    __syncthreads();
    writeV(vb0, vb1);
    __syncthreads();  // publish KsB(t+1) + Vt(t+1)
    if (t + 2 < 64) {
      stageK(KsA, (t + 2) * 64);
      loadV((t + 2) * 64, va0, va1);
    }
    compute(KsB);
  }

  // epilogue: normalize by acc_d, hi plane then lo plane via per-wave LDS
  #pragma unroll
  for (int mt = 0; mt < 2; ++mt) {
    #pragma unroll
    for (int r = 0; r < 4; ++r) {
      const float inv = 1.f / acc_d[mt][r];
      const int row = mt * 16 + 4 * lg + r;
      const int rsw = (row & 7) << 4;
      #pragma unroll
      for (int dt = 0; dt < 4; ++dt) {
        const float v = acc_o[mt][dt][r] * inv;
        acc_o[mt][dt][r] = v;
        const int col = dt * 16 + lr;
        *(bf16_t*)(psw + ((row * 128 + col * 2) ^ rsw)) = (bf16_t)v;
      }
    }
  }
  const int row2 = l & 31, hf = l >> 5;
  {
    bf16_t* orow = Oh + (size_t)(b * 4096 + q0 + row2) * 512 + h * 64 + hf * 32;
    #pragma unroll
    for (int c = 0; c < 4; ++c) {
      const bf16x8 vv =
          *(const bf16x8*)(psw + ((row2 * 128 + hf * 64 + c * 16) ^ ((row2 & 7) << 4)));
      *(bf16x8*)(orow + c * 8) = vv;
    }
  }
  #pragma unroll
  for (int mt = 0; mt < 2; ++mt) {
    #pragma unroll
    for (int r = 0; r < 4; ++r) {
      const int row = mt * 16 + 4 * lg + r;
      const int rsw = (row & 7) << 4;
      #pragma unroll
      for (int dt = 0; dt < 4; ++dt) {
        const float v = acc_o[mt][dt][r];
        const bf16_t hi = (bf16_t)v;
        const bf16_t lo = (bf16_t)(v - (float)hi);
        const int col = dt * 16 + lr;
        *(bf16_t*)(psw + ((row * 128 + col * 2) ^ rsw)) = lo;
      }
    }
  }
  {
    bf16_t* orow = Ol + (size_t)(b * 4096 + q0 + row2) * 512 + h * 64 + hf * 32;
    #pragma unroll
    for (int c = 0; c < 4; ++c) {
      const bf16x8 vv =
          *(const bf16x8*)(psw + ((row2 * 128 + hf * 64 + c * 16) ^ ((row2 & 7) << 4)));
      *(bf16x8*)(orow + c * 8) = vv;
    }
  }
}

// ------------------------------------------------------------- proj GEMM
__global__ __launch_bounds__(256) void gemm_proj(const bf16_t* __restrict__ Oh,
                                                 const bf16_t* __restrict__ Ol,
                                                 const bf16_t* __restrict__ Wph,
                                                 const bf16_t* __restrict__ Wpl,
                                                 const float* __restrict__ bproj,
                                                 float* __restrict__ Y) {
  extern __shared__ char smem[];
  char* const Ah = smem;
  char* const Al = smem + 16384;
  char* const Bh = smem + 32768;
  char* const Bl = smem + 49152;
  const int pos0 = blockIdx.y * 128;
  const int oc0 = blockIdx.x * 128;
  const int tid = threadIdx.x;
  const int l = tid & 63, w = tid >> 6;
  const int wr = w >> 1, wc = w & 1;
  f32x4 acc[4][4] = {};
  for (int kt = 0; kt < 512; kt += 64) {
    __syncthreads();
    #pragma unroll
    for (int i = 0; i < 4; ++i) {
      const int chunk = tid + 256 * i;
      const int row = chunk >> 3;
      const int cp = (chunk & 7) ^ (row & 7);  // pre-swizzled source
      const size_t offA = (size_t)(pos0 + row) * 512 + kt + cp * 8;
      const size_t offB = (size_t)(oc0 + row) * 512 + kt + cp * 8;
      __builtin_amdgcn_global_load_lds(
          (const __attribute__((address_space(1))) void*)(Oh + offA),
          (__attribute__((address_space(3))) void*)(Ah + chunk * 16), 16, 0, 0);
      __builtin_amdgcn_global_load_lds(
          (const __attribute__((address_space(1))) void*)(Ol + offA),
          (__attribute__((address_space(3))) void*)(Al + chunk * 16), 16, 0, 0);
      __builtin_amdgcn_global_load_lds(
          (const __attribute__((address_space(1))) void*)(Wph + offB),
          (__attribute__((address_space(3))) void*)(Bh + chunk * 16), 16, 0, 0);
      __builtin_amdgcn_global_load_lds(
          (const __attribute__((address_space(1))) void*)(Wpl + offB),
          (__attribute__((address_space(3))) void*)(Bl + chunk * 16), 16, 0, 0);
    }
    __syncthreads();
    #pragma unroll
    for (int ks = 0; ks < 2; ++ks) {
      bf16x8 ah[4], al[4], bh[4], bl[4];
      #pragma unroll
      for (int mt = 0; mt < 4; ++mt) {
        const int row = wr * 64 + mt * 16 + (l & 15);
        const int off = row * 128 + ((ks * 64 + (l >> 4) * 16) ^ ((row & 7) << 4));
        ah[mt] = *(const bf16x8*)(Ah + off);
        al[mt] = *(const bf16x8*)(Al + off);
      }
      #pragma unroll
      for (int nt = 0; nt < 4; ++nt) {
        const int row = wc * 64 + nt * 16 + (l & 15);
        const int off = row * 128 + ((ks * 64 + (l >> 4) * 16) ^ ((row & 7) << 4));
        bh[nt] = *(const bf16x8*)(Bh + off);
        bl[nt] = *(const bf16x8*)(Bl + off);
      }
      #pragma unroll
      for (int mt = 0; mt < 4; ++mt)
        #pragma unroll
        for (int nt = 0; nt < 4; ++nt) {
          acc[mt][nt] = MFMA16(ah[mt], bh[nt], acc[mt][nt]);
          acc[mt][nt] = MFMA16(ah[mt], bl[nt], acc[mt][nt]);
          acc[mt][nt] = MFMA16(al[mt], bh[nt], acc[mt][nt]);
        }
    }
  }
  #pragma unroll
  for (int mt = 0; mt < 4; ++mt) {
    const int posb = pos0 + wr * 64 + mt * 16 + 4 * (l >> 4);
    const int bb_ = posb >> 12, p = posb & 4095;
    #pragma unroll
    for (int nt = 0; nt < 4; ++nt) {
      const int oc = oc0 + wc * 64 + nt * 16 + (l & 15);
      const float bias = bproj[oc];
      float4 v;
      v.x = acc[mt][nt][0] + bias;
      v.y = acc[mt][nt][1] + bias;
      v.z = acc[mt][nt][2] + bias;
      v.w = acc[mt][nt][3] + bias;
      *(float4*)(Y + ((size_t)(bb_ * 512 + oc)) * 4096 + p) = v;
    }
  }
}

// ------------------------------------------------------------- launch
extern "C" void kernel_launch(void* const* d_in, const int* in_sizes, int n_in,
                              void* d_out, int out_size, void* d_ws, size_t ws_size,
                              hipStream_t stream) {
  const float* X = (const float*)d_in[0];
  const float* gamma = (const float*)d_in[1];
  const float* beta = (const float*)d_in[2];
  const float* Wqkv = (const float*)d_in[3];
  const float* bqkv = (const float*)d_in[4];
  const float* Wproj = (const float*)d_in[5];
  const float* bproj = (const float*)d_in[6];
  float* Y = (float*)d_out;
  char* ws = (char*)d_ws;

  bf16_t* Wq_hi = (bf16_t*)(ws + 0);
  bf16_t* Wq_lo = (bf16_t*)(ws + 1572864);
  bf16_t* Wp_hi = (bf16_t*)(ws + 3145728);
  bf16_t* Wp_lo = (bf16_t*)(ws + 3670016);
  bf16_t* T_hi = (bf16_t*)(ws + 4194304);
  bf16_t* T_lo = (bf16_t*)(ws + 20971520);
  bf16_t* QKVb = (bf16_t*)(ws + 37748736);
  bf16_t* O_hi = T_hi;  // alias: T dead after gemm_qkv
  bf16_t* O_lo = T_lo;

  cvt_kernel<<<1024, 256, 0, stream>>>(Wqkv, Wproj, Wq_hi, Wq_lo, Wp_hi, Wp_lo);
  ln_kernel<<<dim3(128, 4), 256, 0, stream>>>(X, gamma, beta, T_hi, T_lo);
  gemm_qkv<<<dim3(128, 12), 256, 65536, stream>>>(Wq_hi, Wq_lo, T_hi, T_lo, bqkv, QKVb);
  attn_kernel<<<dim3(1024), 256, 0, stream>>>(QKVb, O_hi, O_lo);
  gemm_proj<<<dim3(4, 128), 256, 65536, stream>>>(O_hi, O_lo, Wp_hi, Wp_lo, bproj, Y);
}

// Round 5
// 437.877 us; speedup vs baseline: 1.2158x; 1.2158x over previous
//
#include <hip/hip_runtime.h>
#include <hip/hip_bf16.h>

typedef __bf16 bf16_t;
typedef __attribute__((ext_vector_type(8))) __bf16 bf16x8;
typedef __attribute__((ext_vector_type(4))) __bf16 bf16x4;
typedef __attribute__((ext_vector_type(4))) float f32x4;

#define MFMA16(A, B, C) __builtin_amdgcn_mfma_f32_16x16x32_bf16((A), (B), (C), 0, 0, 0)

#if __has_builtin(__builtin_amdgcn_exp2f)
#define EXP2F(x) __builtin_amdgcn_exp2f(x)
#else
#define EXP2F(x) exp2f(x)
#endif

// log2(e)/8 : folded into the Q plane in gemm_qkv's fp32 epilogue
#define QSCALE 0.1803368801111244f

// ------------------------------------------------------------- weights cvt
__global__ __launch_bounds__(256) void cvt_kernel(const float* __restrict__ Wq,
                                                  const float* __restrict__ Wp,
                                                  bf16_t* __restrict__ qh,
                                                  bf16_t* __restrict__ ql,
                                                  bf16_t* __restrict__ ph,
                                                  bf16_t* __restrict__ pl) {
  const int i = (blockIdx.x * 256 + threadIdx.x) * 4;
  if (i < 786432) {
    const float4 v = *(const float4*)(Wq + i);
    const float vv[4] = {v.x, v.y, v.z, v.w};
    bf16x4 h, l;
    #pragma unroll
    for (int j = 0; j < 4; ++j) {
      h[j] = (bf16_t)vv[j];
      l[j] = (bf16_t)(vv[j] - (float)h[j]);
    }
    *(bf16x4*)(qh + i) = h;
    *(bf16x4*)(ql + i) = l;
  } else {
    const int j0 = i - 786432;
    const float4 v = *(const float4*)(Wp + j0);
    const float vv[4] = {v.x, v.y, v.z, v.w};
    bf16x4 h, l;
    #pragma unroll
    for (int j = 0; j < 4; ++j) {
      h[j] = (bf16_t)vv[j];
      l[j] = (bf16_t)(vv[j] - (float)h[j]);
    }
    *(bf16x4*)(ph + j0) = h;
    *(bf16x4*)(pl + j0) = l;
  }
}

// ------------------------------------------------------------- LayerNorm
__global__ __launch_bounds__(256) void ln_kernel(const float* __restrict__ X,
                                                 const float* __restrict__ gamma,
                                                 const float* __restrict__ beta,
                                                 bf16_t* __restrict__ Th,
                                                 bf16_t* __restrict__ Tl) {
  __shared__ __align__(16) bf16_t tile[512 * 32];  // [c][pi]
  __shared__ float red1[8][32];
  __shared__ float red2[8][32];
  __shared__ float smu[32], srs[32];
  __shared__ float sg[512], sb[512];
  const int tid = threadIdx.x;
  const int g = tid >> 5, pi = tid & 31;
  const int b = blockIdx.y;
  const int p0 = blockIdx.x * 32;
  sg[tid] = gamma[tid];
  sg[tid + 256] = gamma[tid + 256];
  sb[tid] = beta[tid];
  sb[tid + 256] = beta[tid + 256];
  const float* Xb = X + ((size_t)b * 512) * 4096 + p0;
  float s1 = 0.f, s2 = 0.f;
  #pragma unroll 4
  for (int c = g * 64; c < g * 64 + 64; ++c) {
    const float x = Xb[(size_t)c * 4096 + pi];
    tile[c * 32 + pi] = (bf16_t)x;
    s1 += x;
    s2 += x * x;
  }
  red1[g][pi] = s1;
  red2[g][pi] = s2;
  __syncthreads();
  if (tid < 32) {
    float a = 0.f, q = 0.f;
    #pragma unroll
    for (int k = 0; k < 8; ++k) {
      a += red1[k][tid];
      q += red2[k][tid];
    }
    const float mu = a * (1.f / 512.f);
    const float var = q * (1.f / 512.f) - mu * mu;
    smu[tid] = mu;
    srs[tid] = rsqrtf(var + 1e-5f);
  }
  __syncthreads();
  const int pi2 = tid >> 3, qq = tid & 7;
  const float mu = smu[pi2], rs = srs[pi2];
  const size_t outoff = ((size_t)(b * 4096 + p0 + pi2)) * 512;
  #pragma unroll
  for (int ii = 0; ii < 8; ++ii) {
    const int c0 = qq * 64 + ii * 8;
    bf16x8 ph, pl;
    #pragma unroll
    for (int j = 0; j < 8; ++j) {
      const float x = (float)tile[(c0 + j) * 32 + pi2];
      const float y = (x - mu) * rs * sg[c0 + j] + sb[c0 + j];
      const bf16_t hi = (bf16_t)y;
      ph[j] = hi;
      pl[j] = (bf16_t)(y - (float)hi);
    }
    *(bf16x8*)(Th + outoff + c0) = ph;
    *(bf16x8*)(Tl + outoff + c0) = pl;
  }
}

// ------------------------------------------------------------- QKV GEMM
// global_load_lds staging (pre-swizzled source), 3-term hi/lo split.
// Q-region outputs pre-scaled by log2(e)/8 in fp32 (exact for attn's exp2).
__global__ __launch_bounds__(256) void gemm_qkv(const bf16_t* __restrict__ Wqh,
                                                const bf16_t* __restrict__ Wql,
                                                const bf16_t* __restrict__ Th,
                                                const bf16_t* __restrict__ Tl,
                                                const float* __restrict__ bqkv,
                                                bf16_t* __restrict__ QKV) {
  extern __shared__ char smem[];
  char* const Ah = smem;
  char* const Al = smem + 16384;
  char* const Bh = smem + 32768;
  char* const Bl = smem + 49152;
  const int pos0 = blockIdx.x * 128;
  const int oc0 = blockIdx.y * 128;
  const int tid = threadIdx.x;
  const int l = tid & 63, w = tid >> 6;
  const int wr = w >> 1, wc = w & 1;
  f32x4 acc[4][4] = {};
  for (int kt = 0; kt < 512; kt += 64) {
    __syncthreads();
    #pragma unroll
    for (int i = 0; i < 4; ++i) {
      const int chunk = tid + 256 * i;
      const int row = chunk >> 3;
      const int cp = (chunk & 7) ^ (row & 7);  // pre-swizzled source
      const size_t offA = (size_t)(oc0 + row) * 512 + kt + cp * 8;
      const size_t offB = (size_t)(pos0 + row) * 512 + kt + cp * 8;
      __builtin_amdgcn_global_load_lds(
          (const __attribute__((address_space(1))) void*)(Wqh + offA),
          (__attribute__((address_space(3))) void*)(Ah + chunk * 16), 16, 0, 0);
      __builtin_amdgcn_global_load_lds(
          (const __attribute__((address_space(1))) void*)(Wql + offA),
          (__attribute__((address_space(3))) void*)(Al + chunk * 16), 16, 0, 0);
      __builtin_amdgcn_global_load_lds(
          (const __attribute__((address_space(1))) void*)(Th + offB),
          (__attribute__((address_space(3))) void*)(Bh + chunk * 16), 16, 0, 0);
      __builtin_amdgcn_global_load_lds(
          (const __attribute__((address_space(1))) void*)(Tl + offB),
          (__attribute__((address_space(3))) void*)(Bl + chunk * 16), 16, 0, 0);
    }
    __syncthreads();
    #pragma unroll
    for (int ks = 0; ks < 2; ++ks) {
      bf16x8 ah[4], al[4], bh[4], bl[4];
      #pragma unroll
      for (int mt = 0; mt < 4; ++mt) {
        const int row = wr * 64 + mt * 16 + (l & 15);
        const int off = row * 128 + ((ks * 64 + (l >> 4) * 16) ^ ((row & 7) << 4));
        ah[mt] = *(const bf16x8*)(Ah + off);
        al[mt] = *(const bf16x8*)(Al + off);
      }
      #pragma unroll
      for (int nt = 0; nt < 4; ++nt) {
        const int row = wc * 64 + nt * 16 + (l & 15);
        const int off = row * 128 + ((ks * 64 + (l >> 4) * 16) ^ ((row & 7) << 4));
        bh[nt] = *(const bf16x8*)(Bh + off);
        bl[nt] = *(const bf16x8*)(Bl + off);
      }
      #pragma unroll
      for (int mt = 0; mt < 4; ++mt)
        #pragma unroll
        for (int nt = 0; nt < 4; ++nt) {
          acc[mt][nt] = MFMA16(ah[mt], bh[nt], acc[mt][nt]);
          acc[mt][nt] = MFMA16(ah[mt], bl[nt], acc[mt][nt]);
          acc[mt][nt] = MFMA16(al[mt], bh[nt], acc[mt][nt]);
        }
    }
  }
  #pragma unroll
  for (int mt = 0; mt < 4; ++mt) {
    const int ocb = oc0 + wr * 64 + mt * 16 + 4 * (l >> 4);
    const float4 bias = *(const float4*)(bqkv + ocb);
    const float qs = ((ocb % 192) < 64) ? QSCALE : 1.0f;
    #pragma unroll
    for (int nt = 0; nt < 4; ++nt) {
      const int pos = pos0 + wc * 64 + nt * 16 + (l & 15);
      bf16x4 o;
      o[0] = (bf16_t)((acc[mt][nt][0] + bias.x) * qs);
      o[1] = (bf16_t)((acc[mt][nt][1] + bias.y) * qs);
      o[2] = (bf16_t)((acc[mt][nt][2] + bias.z) * qs);
      o[3] = (bf16_t)((acc[mt][nt][3] + bias.w) * qs);
      *(bf16x4*)(QKV + (size_t)pos * 1536 + ocb) = o;
    }
  }
}

// ------------------------------------------------------------- attention
// Swapped QK^T, exp2 no-max softmax (Q pre-scaled by log2e/8 upstream),
// denominator via MFMA-with-ones, K via global_load_lds double-buffer,
// XOR-swizzled Vt, LDS = 40960 B -> 4 blocks/CU (LDS-gated; VGPR free).
__global__ __launch_bounds__(256) void attn_kernel(const bf16_t* __restrict__ QKV,
                                                   bf16_t* __restrict__ Oh,
                                                   bf16_t* __restrict__ Ol) {
  const int o = blockIdx.x;
  const int sid = (o & 7) * 128 + (o >> 3);  // 4 (b,h) pairs per XCD
  const int qt = sid & 31;
  const int bh = sid >> 5;
  const int b = bh >> 3, h = bh & 7;
  const int tid = threadIdx.x;
  const int l = tid & 63, w = tid >> 6;
  const int lg = l >> 4, lr = l & 15;

  __shared__ __align__(16) bf16_t KsA[64 * 64];    // [key][d] XOR-swizzled, 8KB
  __shared__ __align__(16) bf16_t KsB[64 * 64];    // 8KB
  __shared__ __align__(16) bf16_t Vt[64 * 64];     // [d][key] XOR-swizzled, 8KB
  __shared__ __align__(16) bf16_t Ps[4][32 * 64];  // per-wave P / O staging, 16KB

  const bf16_t* base = QKV + (size_t)(b * 4096) * 1536 + h * 192;
  const bf16_t* kbase = base + 64;
  const bf16_t* vbase = base + 128;
  const int q0 = qt * 128 + w * 32;

  // Q fragments (already scaled by log2e/8 upstream in fp32)
  bf16x8 qf[2][2];
  #pragma unroll
  for (int mq = 0; mq < 2; ++mq)
    #pragma unroll
    for (int ks = 0; ks < 2; ++ks)
      qf[mq][ks] = *(const bf16x8*)(base + (size_t)(q0 + mq * 16 + lr) * 1536 +
                                    ks * 32 + 8 * lg);

  bf16x8 onesb;
  {
    const bf16_t one = (bf16_t)1.0f;
    #pragma unroll
    for (int j = 0; j < 8; ++j) onesb[j] = one;
  }

  f32x4 acc_o[2][4] = {};
  f32x4 acc_d[2] = {};
  char* const psw = (char*)&Ps[w][0];

  auto stageK = [&](bf16_t* dst, int k0) {
    #pragma unroll
    for (int i = 0; i < 2; ++i) {
      const int c = tid + 256 * i;
      const int row = c >> 3;
      const int cp = (c & 7) ^ (row & 7);  // pre-swizzled source
      const bf16_t* g = kbase + (size_t)(k0 + row) * 1536 + cp * 8;
      __builtin_amdgcn_global_load_lds(
          (const __attribute__((address_space(1))) void*)g,
          (__attribute__((address_space(3))) void*)((char*)dst + c * 16), 16, 0, 0);
    }
  };
  auto loadV = [&](int k0, bf16x8& v0, bf16x8& v1) {
    const bf16_t* vs = vbase + (size_t)(k0 + l) * 1536 + w * 16;
    v0 = *(const bf16x8*)vs;
    v1 = *(const bf16x8*)(vs + 8);
  };
  auto writeV = [&](bf16x8 v0, bf16x8 v1) {
    char* const vt = (char*)Vt;
    #pragma unroll
    for (int j = 0; j < 8; ++j) {
      const int d0 = w * 16 + j, d1 = w * 16 + 8 + j;
      *(bf16_t*)(vt + d0 * 128 + ((2 * l) ^ ((d0 & 7) << 4))) = v0[j];
      *(bf16_t*)(vt + d1 * 128 + ((2 * l) ^ ((d1 & 7) << 4))) = v1[j];
    }
  };
  auto compute = [&](const bf16_t* Kbuf) {
    // S^T = mfma(K, Q): cols = q (lr), rows = key kt*16 + 4*lg + r
    f32x4 st[4][2] = {};
    __builtin_amdgcn_s_setprio(1);
    #pragma unroll
    for (int ks = 0; ks < 2; ++ks) {
      bf16x8 kb[4];
      #pragma unroll
      for (int kt = 0; kt < 4; ++kt) {
        const int row = kt * 16 + lr;
        kb[kt] = *(const bf16x8*)((const char*)Kbuf + row * 128 +
                                  ((ks * 64 + lg * 16) ^ ((row & 7) << 4)));
      }
      #pragma unroll
      for (int kt = 0; kt < 4; ++kt) {
        st[kt][0] = MFMA16(kb[kt], qf[0][ks], st[kt][0]);
        st[kt][1] = MFMA16(kb[kt], qf[1][ks], st[kt][1]);
      }
    }
    __builtin_amdgcn_s_setprio(0);
    // p = exp2(s'), packed bf16 P into per-wave LDS
    #pragma unroll
    for (int mq = 0; mq < 2; ++mq) {
      const int prow = mq * 16 + lr;
      const int rs = (prow & 7) << 4;
      #pragma unroll
      for (int kt = 0; kt < 4; ++kt) {
        bf16x4 pk;
        pk[0] = (bf16_t)EXP2F(st[kt][mq][0]);
        pk[1] = (bf16_t)EXP2F(st[kt][mq][1]);
        pk[2] = (bf16_t)EXP2F(st[kt][mq][2]);
        pk[3] = (bf16_t)EXP2F(st[kt][mq][3]);
        *(bf16x4*)(psw + prow * 128 + ((kt * 32 + lg * 8) ^ rs)) = pk;
      }
    }
    // O += P V ; denom += P * ones (C/D layout matches acc_o rows)
    #pragma unroll
    for (int ks = 0; ks < 2; ++ks) {
      bf16x8 pa[2], vb[4];
      #pragma unroll
      for (int mt = 0; mt < 2; ++mt) {
        const int row = mt * 16 + lr;
        pa[mt] = *(const bf16x8*)(psw + row * 128 +
                                  ((ks * 64 + lg * 16) ^ ((row & 7) << 4)));
      }
      #pragma unroll
      for (int dt = 0; dt < 4; ++dt) {
        const int row = dt * 16 + lr;
        vb[dt] = *(const bf16x8*)((const char*)Vt + row * 128 +
                                  ((ks * 64 + lg * 16) ^ ((row & 7) << 4)));
      }
      __builtin_amdgcn_s_setprio(1);
      #pragma unroll
      for (int mt = 0; mt < 2; ++mt) {
        #pragma unroll
        for (int dt = 0; dt < 4; ++dt)
          acc_o[mt][dt] = MFMA16(pa[mt], vb[dt], acc_o[mt][dt]);
        acc_d[mt] = MFMA16(pa[mt], onesb, acc_d[mt]);
      }
      __builtin_amdgcn_s_setprio(0);
    }
  };

  // prologue
  stageK(KsA, 0);
  bf16x8 va0, va1, vb0, vb1;
  loadV(0, va0, va1);

  for (int t = 0; t < 64; t += 2) {
    __syncthreads();
    writeV(va0, va1);
    __syncthreads();  // publish KsA(t) + Vt(t)
    stageK(KsB, (t + 1) * 64);
    loadV((t + 1) * 64, vb0, vb1);
    compute(KsA);

    __syncthreads();
    writeV(vb0, vb1);
    __syncthreads();  // publish KsB(t+1) + Vt(t+1)
    if (t + 2 < 64) {
      stageK(KsA, (t + 2) * 64);
      loadV((t + 2) * 64, va0, va1);
    }
    compute(KsB);
  }

  // epilogue: normalize by acc_d, hi plane then lo plane via per-wave LDS
  #pragma unroll
  for (int mt = 0; mt < 2; ++mt) {
    #pragma unroll
    for (int r = 0; r < 4; ++r) {
      const float inv = 1.f / acc_d[mt][r];
      const int row = mt * 16 + 4 * lg + r;
      const int rsw = (row & 7) << 4;
      #pragma unroll
      for (int dt = 0; dt < 4; ++dt) {
        const float v = acc_o[mt][dt][r] * inv;
        acc_o[mt][dt][r] = v;
        const int col = dt * 16 + lr;
        *(bf16_t*)(psw + ((row * 128 + col * 2) ^ rsw)) = (bf16_t)v;
      }
    }
  }
  const int row2 = l & 31, hf = l >> 5;
  {
    bf16_t* orow = Oh + (size_t)(b * 4096 + q0 + row2) * 512 + h * 64 + hf * 32;
    #pragma unroll
    for (int c = 0; c < 4; ++c) {
      const bf16x8 vv =
          *(const bf16x8*)(psw + ((row2 * 128 + hf * 64 + c * 16) ^ ((row2 & 7) << 4)));
      *(bf16x8*)(orow + c * 8) = vv;
    }
  }
  #pragma unroll
  for (int mt = 0; mt < 2; ++mt) {
    #pragma unroll
    for (int r = 0; r < 4; ++r) {
      const int row = mt * 16 + 4 * lg + r;
      const int rsw = (row & 7) << 4;
      #pragma unroll
      for (int dt = 0; dt < 4; ++dt) {
        const float v = acc_o[mt][dt][r];
        const bf16_t hi = (bf16_t)v;
        const bf16_t lo = (bf16_t)(v - (float)hi);
        const int col = dt * 16 + lr;
        *(bf16_t*)(psw + ((row * 128 + col * 2) ^ rsw)) = lo;
      }
    }
  }
  {
    bf16_t* orow = Ol + (size_t)(b * 4096 + q0 + row2) * 512 + h * 64 + hf * 32;
    #pragma unroll
    for (int c = 0; c < 4; ++c) {
      const bf16x8 vv =
          *(const bf16x8*)(psw + ((row2 * 128 + hf * 64 + c * 16) ^ ((row2 & 7) << 4)));
      *(bf16x8*)(orow + c * 8) = vv;
    }
  }
}

// ------------------------------------------------------------- proj GEMM
__global__ __launch_bounds__(256) void gemm_proj(const bf16_t* __restrict__ Oh,
                                                 const bf16_t* __restrict__ Ol,
                                                 const bf16_t* __restrict__ Wph,
                                                 const bf16_t* __restrict__ Wpl,
                                                 const float* __restrict__ bproj,
                                                 float* __restrict__ Y) {
  extern __shared__ char smem[];
  char* const Ah = smem;
  char* const Al = smem + 16384;
  char* const Bh = smem + 32768;
  char* const Bl = smem + 49152;
  const int pos0 = blockIdx.y * 128;
  const int oc0 = blockIdx.x * 128;
  const int tid = threadIdx.x;
  const int l = tid & 63, w = tid >> 6;
  const int wr = w >> 1, wc = w & 1;
  f32x4 acc[4][4] = {};
  for (int kt = 0; kt < 512; kt += 64) {
    __syncthreads();
    #pragma unroll
    for (int i = 0; i < 4; ++i) {
      const int chunk = tid + 256 * i;
      const int row = chunk >> 3;
      const int cp = (chunk & 7) ^ (row & 7);  // pre-swizzled source
      const size_t offA = (size_t)(pos0 + row) * 512 + kt + cp * 8;
      const size_t offB = (size_t)(oc0 + row) * 512 + kt + cp * 8;
      __builtin_amdgcn_global_load_lds(
          (const __attribute__((address_space(1))) void*)(Oh + offA),
          (__attribute__((address_space(3))) void*)(Ah + chunk * 16), 16, 0, 0);
      __builtin_amdgcn_global_load_lds(
          (const __attribute__((address_space(1))) void*)(Ol + offA),
          (__attribute__((address_space(3))) void*)(Al + chunk * 16), 16, 0, 0);
      __builtin_amdgcn_global_load_lds(
          (const __attribute__((address_space(1))) void*)(Wph + offB),
          (__attribute__((address_space(3))) void*)(Bh + chunk * 16), 16, 0, 0);
      __builtin_amdgcn_global_load_lds(
          (const __attribute__((address_space(1))) void*)(Wpl + offB),
          (__attribute__((address_space(3))) void*)(Bl + chunk * 16), 16, 0, 0);
    }
    __syncthreads();
    #pragma unroll
    for (int ks = 0; ks < 2; ++ks) {
      bf16x8 ah[4], al[4], bh[4], bl[4];
      #pragma unroll
      for (int mt = 0; mt < 4; ++mt) {
        const int row = wr * 64 + mt * 16 + (l & 15);
        const int off = row * 128 + ((ks * 64 + (l >> 4) * 16) ^ ((row & 7) << 4));
        ah[mt] = *(const bf16x8*)(Ah + off);
        al[mt] = *(const bf16x8*)(Al + off);
      }
      #pragma unroll
      for (int nt = 0; nt < 4; ++nt) {
        const int row = wc * 64 + nt * 16 + (l & 15);
        const int off = row * 128 + ((ks * 64 + (l >> 4) * 16) ^ ((row & 7) << 4));
        bh[nt] = *(const bf16x8*)(Bh + off);
        bl[nt] = *(const bf16x8*)(Bl + off);
      }
      #pragma unroll
      for (int mt = 0; mt < 4; ++mt)
        #pragma unroll
        for (int nt = 0; nt < 4; ++nt) {
          acc[mt][nt] = MFMA16(ah[mt], bh[nt], acc[mt][nt]);
          acc[mt][nt] = MFMA16(ah[mt], bl[nt], acc[mt][nt]);
          acc[mt][nt] = MFMA16(al[mt], bh[nt], acc[mt][nt]);
        }
    }
  }
  #pragma unroll
  for (int mt = 0; mt < 4; ++mt) {
    const int posb = pos0 + wr * 64 + mt * 16 + 4 * (l >> 4);
    const int bb_ = posb >> 12, p = posb & 4095;
    #pragma unroll
    for (int nt = 0; nt < 4; ++nt) {
      const int oc = oc0 + wc * 64 + nt * 16 + (l & 15);
      const float bias = bproj[oc];
      float4 v;
      v.x = acc[mt][nt][0] + bias;
      v.y = acc[mt][nt][1] + bias;
      v.z = acc[mt][nt][2] + bias;
      v.w = acc[mt][nt][3] + bias;
      *(float4*)(Y + ((size_t)(bb_ * 512 + oc)) * 4096 + p) = v;
    }
  }
}

// ------------------------------------------------------------- launch
extern "C" void kernel_launch(void* const* d_in, const int* in_sizes, int n_in,
                              void* d_out, int out_size, void* d_ws, size_t ws_size,
                              hipStream_t stream) {
  const float* X = (const float*)d_in[0];
  const float* gamma = (const float*)d_in[1];
  const float* beta = (const float*)d_in[2];
  const float* Wqkv = (const float*)d_in[3];
  const float* bqkv = (const float*)d_in[4];
  const float* Wproj = (const float*)d_in[5];
  const float* bproj = (const float*)d_in[6];
  float* Y = (float*)d_out;
  char* ws = (char*)d_ws;

  bf16_t* Wq_hi = (bf16_t*)(ws + 0);
  bf16_t* Wq_lo = (bf16_t*)(ws + 1572864);
  bf16_t* Wp_hi = (bf16_t*)(ws + 3145728);
  bf16_t* Wp_lo = (bf16_t*)(ws + 3670016);
  bf16_t* T_hi = (bf16_t*)(ws + 4194304);
  bf16_t* T_lo = (bf16_t*)(ws + 20971520);
  bf16_t* QKVb = (bf16_t*)(ws + 37748736);
  bf16_t* O_hi = T_hi;  // alias: T dead after gemm_qkv
  bf16_t* O_lo = T_lo;

  cvt_kernel<<<1024, 256, 0, stream>>>(Wqkv, Wproj, Wq_hi, Wq_lo, Wp_hi, Wp_lo);
  ln_kernel<<<dim3(128, 4), 256, 0, stream>>>(X, gamma, beta, T_hi, T_lo);
  gemm_qkv<<<dim3(128, 12), 256, 65536, stream>>>(Wq_hi, Wq_lo, T_hi, T_lo, bqkv, QKVb);
  attn_kernel<<<dim3(1024), 256, 0, stream>>>(QKVb, O_hi, O_lo);
  gemm_proj<<<dim3(4, 128), 256, 65536, stream>>>(O_hi, O_lo, Wp_hi, Wp_lo, bproj, Y);
}

// Round 7
// 402.460 us; speedup vs baseline: 1.3228x; 1.0880x over previous
//
#include <hip/hip_runtime.h>
#include <hip/hip_bf16.h>

typedef __bf16 bf16_t;
typedef __attribute__((ext_vector_type(8))) __bf16 bf16x8;
typedef __attribute__((ext_vector_type(4))) __bf16 bf16x4;
typedef __attribute__((ext_vector_type(4))) float f32x4;

#define MFMA16(A, B, C) __builtin_amdgcn_mfma_f32_16x16x32_bf16((A), (B), (C), 0, 0, 0)

#if __has_builtin(__builtin_amdgcn_exp2f)
#define EXP2F(x) __builtin_amdgcn_exp2f(x)
#else
#define EXP2F(x) exp2f(x)
#endif

// log2(e)/8 : folded into the Q plane in gemm_qkv's fp32 epilogue
#define QSCALE 0.1803368801111244f

// ------------------------------------------------------------- weights cvt
__global__ __launch_bounds__(256) void cvt_kernel(const float* __restrict__ Wq,
                                                  const float* __restrict__ Wp,
                                                  bf16_t* __restrict__ qh,
                                                  bf16_t* __restrict__ ql,
                                                  bf16_t* __restrict__ ph,
                                                  bf16_t* __restrict__ pl) {
  const int i = (blockIdx.x * 256 + threadIdx.x) * 4;
  if (i < 786432) {
    const float4 v = *(const float4*)(Wq + i);
    const float vv[4] = {v.x, v.y, v.z, v.w};
    bf16x4 h, l;
    #pragma unroll
    for (int j = 0; j < 4; ++j) {
      h[j] = (bf16_t)vv[j];
      l[j] = (bf16_t)(vv[j] - (float)h[j]);
    }
    *(bf16x4*)(qh + i) = h;
    *(bf16x4*)(ql + i) = l;
  } else {
    const int j0 = i - 786432;
    const float4 v = *(const float4*)(Wp + j0);
    const float vv[4] = {v.x, v.y, v.z, v.w};
    bf16x4 h, l;
    #pragma unroll
    for (int j = 0; j < 4; ++j) {
      h[j] = (bf16_t)vv[j];
      l[j] = (bf16_t)(vv[j] - (float)h[j]);
    }
    *(bf16x4*)(ph + j0) = h;
    *(bf16x4*)(pl + j0) = l;
  }
}

// ------------------------------------------------------------- LayerNorm
__global__ __launch_bounds__(256) void ln_kernel(const float* __restrict__ X,
                                                 const float* __restrict__ gamma,
                                                 const float* __restrict__ beta,
                                                 bf16_t* __restrict__ Th,
                                                 bf16_t* __restrict__ Tl) {
  __shared__ __align__(16) bf16_t tile[512 * 32];  // [c][pi]
  __shared__ float red1[8][32];
  __shared__ float red2[8][32];
  __shared__ float smu[32], srs[32];
  __shared__ float sg[512], sb[512];
  const int tid = threadIdx.x;
  const int g = tid >> 5, pi = tid & 31;
  const int b = blockIdx.y;
  const int p0 = blockIdx.x * 32;
  sg[tid] = gamma[tid];
  sg[tid + 256] = gamma[tid + 256];
  sb[tid] = beta[tid];
  sb[tid + 256] = beta[tid + 256];
  const float* Xb = X + ((size_t)b * 512) * 4096 + p0;
  float s1 = 0.f, s2 = 0.f;
  #pragma unroll 4
  for (int c = g * 64; c < g * 64 + 64; ++c) {
    const float x = Xb[(size_t)c * 4096 + pi];
    tile[c * 32 + pi] = (bf16_t)x;
    s1 += x;
    s2 += x * x;
  }
  red1[g][pi] = s1;
  red2[g][pi] = s2;
  __syncthreads();
  if (tid < 32) {
    float a = 0.f, q = 0.f;
    #pragma unroll
    for (int k = 0; k < 8; ++k) {
      a += red1[k][tid];
      q += red2[k][tid];
    }
    const float mu = a * (1.f / 512.f);
    const float var = q * (1.f / 512.f) - mu * mu;
    smu[tid] = mu;
    srs[tid] = rsqrtf(var + 1e-5f);
  }
  __syncthreads();
  const int pi2 = tid >> 3, qq = tid & 7;
  const float mu = smu[pi2], rs = srs[pi2];
  const size_t outoff = ((size_t)(b * 4096 + p0 + pi2)) * 512;
  #pragma unroll
  for (int ii = 0; ii < 8; ++ii) {
    const int c0 = qq * 64 + ii * 8;
    bf16x8 ph, pl;
    #pragma unroll
    for (int j = 0; j < 8; ++j) {
      const float x = (float)tile[(c0 + j) * 32 + pi2];
      const float y = (x - mu) * rs * sg[c0 + j] + sb[c0 + j];
      const bf16_t hi = (bf16_t)y;
      ph[j] = hi;
      pl[j] = (bf16_t)(y - (float)hi);
    }
    *(bf16x8*)(Th + outoff + c0) = ph;
    *(bf16x8*)(Tl + outoff + c0) = pl;
  }
}

// ------------------------------------------------------------- QKV GEMM
__global__ __launch_bounds__(256) void gemm_qkv(const bf16_t* __restrict__ Wqh,
                                                const bf16_t* __restrict__ Wql,
                                                const bf16_t* __restrict__ Th,
                                                const bf16_t* __restrict__ Tl,
                                                const float* __restrict__ bqkv,
                                                bf16_t* __restrict__ QKV) {
  extern __shared__ char smem[];
  char* const Ah = smem;
  char* const Al = smem + 16384;
  char* const Bh = smem + 32768;
  char* const Bl = smem + 49152;
  const int pos0 = blockIdx.x * 128;
  const int oc0 = blockIdx.y * 128;
  const int tid = threadIdx.x;
  const int l = tid & 63, w = tid >> 6;
  const int wr = w >> 1, wc = w & 1;
  f32x4 acc[4][4] = {};
  for (int kt = 0; kt < 512; kt += 64) {
    __syncthreads();
    #pragma unroll
    for (int i = 0; i < 4; ++i) {
      const int chunk = tid + 256 * i;
      const int row = chunk >> 3;
      const int cp = (chunk & 7) ^ (row & 7);  // pre-swizzled source
      const size_t offA = (size_t)(oc0 + row) * 512 + kt + cp * 8;
      const size_t offB = (size_t)(pos0 + row) * 512 + kt + cp * 8;
      __builtin_amdgcn_global_load_lds(
          (const __attribute__((address_space(1))) void*)(Wqh + offA),
          (__attribute__((address_space(3))) void*)(Ah + chunk * 16), 16, 0, 0);
      __builtin_amdgcn_global_load_lds(
          (const __attribute__((address_space(1))) void*)(Wql + offA),
          (__attribute__((address_space(3))) void*)(Al + chunk * 16), 16, 0, 0);
      __builtin_amdgcn_global_load_lds(
          (const __attribute__((address_space(1))) void*)(Th + offB),
          (__attribute__((address_space(3))) void*)(Bh + chunk * 16), 16, 0, 0);
      __builtin_amdgcn_global_load_lds(
          (const __attribute__((address_space(1))) void*)(Tl + offB),
          (__attribute__((address_space(3))) void*)(Bl + chunk * 16), 16, 0, 0);
    }
    __syncthreads();
    #pragma unroll
    for (int ks = 0; ks < 2; ++ks) {
      bf16x8 ah[4], al[4], bh[4], bl[4];
      #pragma unroll
      for (int mt = 0; mt < 4; ++mt) {
        const int row = wr * 64 + mt * 16 + (l & 15);
        const int off = row * 128 + ((ks * 64 + (l >> 4) * 16) ^ ((row & 7) << 4));
        ah[mt] = *(const bf16x8*)(Ah + off);
        al[mt] = *(const bf16x8*)(Al + off);
      }
      #pragma unroll
      for (int nt = 0; nt < 4; ++nt) {
        const int row = wc * 64 + nt * 16 + (l & 15);
        const int off = row * 128 + ((ks * 64 + (l >> 4) * 16) ^ ((row & 7) << 4));
        bh[nt] = *(const bf16x8*)(Bh + off);
        bl[nt] = *(const bf16x8*)(Bl + off);
      }
      #pragma unroll
      for (int mt = 0; mt < 4; ++mt)
        #pragma unroll
        for (int nt = 0; nt < 4; ++nt) {
          acc[mt][nt] = MFMA16(ah[mt], bh[nt], acc[mt][nt]);
          acc[mt][nt] = MFMA16(ah[mt], bl[nt], acc[mt][nt]);
          acc[mt][nt] = MFMA16(al[mt], bh[nt], acc[mt][nt]);
        }
    }
  }
  #pragma unroll
  for (int mt = 0; mt < 4; ++mt) {
    const int ocb = oc0 + wr * 64 + mt * 16 + 4 * (l >> 4);
    const float4 bias = *(const float4*)(bqkv + ocb);
    const float qs = ((ocb % 192) < 64) ? QSCALE : 1.0f;
    #pragma unroll
    for (int nt = 0; nt < 4; ++nt) {
      const int pos = pos0 + wc * 64 + nt * 16 + (l & 15);
      bf16x4 o;
      o[0] = (bf16_t)((acc[mt][nt][0] + bias.x) * qs);
      o[1] = (bf16_t)((acc[mt][nt][1] + bias.y) * qs);
      o[2] = (bf16_t)((acc[mt][nt][2] + bias.z) * qs);
      o[3] = (bf16_t)((acc[mt][nt][3] + bias.w) * qs);
      *(bf16x4*)(QKV + (size_t)pos * 1536 + ocb) = o;
    }
  }
}

// ------------------------------------------------------------- attention
// 8 waves / 512 threads per block, QBLK=256 (each wave 32 q-rows).
// Swapped QK^T, exp2 no-max softmax, denominator via MFMA-with-ones,
// per-wave Ps LDS for P redistribution (proven, barrier-free),
// K+V fully double-buffered -> ONE barrier per 64-key tile.
// LDS = 64 KiB -> 2 blocks/CU, grid 512 = exactly 2/CU (no tail).
__global__ __launch_bounds__(512) void attn_kernel(const bf16_t* __restrict__ QKV,
                                                   bf16_t* __restrict__ Oh,
                                                   bf16_t* __restrict__ Ol) {
  const int o = blockIdx.x;
  const int sid = (o & 7) * 64 + (o >> 3);  // 4 (b,h) pairs per XCD
  const int qt = sid & 15;
  const int bh = sid >> 4;
  const int b = bh >> 3, h = bh & 7;
  const int tid = threadIdx.x;
  const int l = tid & 63, w = tid >> 6;
  const int lg = l >> 4, lr = l & 15;

  __shared__ __align__(16) bf16_t KsA[64 * 64];    // [key][d] XOR-swizzled, 8KB
  __shared__ __align__(16) bf16_t KsB[64 * 64];
  __shared__ __align__(16) bf16_t VtA[64 * 64];    // [d][key] XOR-swizzled, 8KB
  __shared__ __align__(16) bf16_t VtB[64 * 64];
  __shared__ __align__(16) bf16_t Ps[8][32 * 64];  // per-wave P / O staging, 32KB

  const bf16_t* base = QKV + (size_t)(b * 4096) * 1536 + h * 192;
  const bf16_t* kbase = base + 64;
  const bf16_t* vbase = base + 128;
  const int q0 = qt * 256 + w * 32;

  // Q fragments (already scaled by log2e/8 upstream in fp32)
  bf16x8 qf[2][2];
  #pragma unroll
  for (int mq = 0; mq < 2; ++mq)
    #pragma unroll
    for (int ks = 0; ks < 2; ++ks)
      qf[mq][ks] = *(const bf16x8*)(base + (size_t)(q0 + mq * 16 + lr) * 1536 +
                                    ks * 32 + 8 * lg);

  bf16x8 onesb;
  {
    const bf16_t one = (bf16_t)1.0f;
    #pragma unroll
    for (int j = 0; j < 8; ++j) onesb[j] = one;
  }

  f32x4 acc_o[2][4] = {};
  f32x4 acc_d[2] = {};
  char* const psw = (char*)&Ps[w][0];

  auto stageK = [&](bf16_t* dst, int k0) {
    // 512 threads x 16B = 8KB tile, one load each
    const int row = tid >> 3;
    const int cp = (tid & 7) ^ (row & 7);  // pre-swizzled source
    const bf16_t* g = kbase + (size_t)(k0 + row) * 1536 + cp * 8;
    __builtin_amdgcn_global_load_lds(
        (const __attribute__((address_space(1))) void*)g,
        (__attribute__((address_space(3))) void*)((char*)dst + tid * 16), 16, 0, 0);
  };
  auto loadV = [&](int k0, bf16x8& v0) {
    // thread t: key = t&63, d-range (t>>6)*8 .. +7
    const bf16_t* vs = vbase + (size_t)(k0 + (tid & 63)) * 1536 + (tid >> 6) * 8;
    v0 = *(const bf16x8*)vs;
  };
  auto writeV = [&](bf16_t* Vt, bf16x8 v0) {
    char* const vt = (char*)Vt;
    const int key = tid & 63;
    #pragma unroll
    for (int j = 0; j < 8; ++j) {
      const int d = (tid >> 6) * 8 + j;
      *(bf16_t*)(vt + d * 128 + ((2 * key) ^ ((d & 7) << 4))) = v0[j];
    }
  };
  auto compute = [&](const bf16_t* Kbuf, const bf16_t* Vbuf) {
    // S^T = mfma(K, Q): cols = q (lr), rows = key kt*16 + 4*lg + r
    f32x4 st[4][2] = {};
    __builtin_amdgcn_s_setprio(1);
    #pragma unroll
    for (int ks = 0; ks < 2; ++ks) {
      bf16x8 kb[4];
      #pragma unroll
      for (int kt = 0; kt < 4; ++kt) {
        const int row = kt * 16 + lr;
        kb[kt] = *(const bf16x8*)((const char*)Kbuf + row * 128 +
                                  ((ks * 64 + lg * 16) ^ ((row & 7) << 4)));
      }
      #pragma unroll
      for (int kt = 0; kt < 4; ++kt) {
        st[kt][0] = MFMA16(kb[kt], qf[0][ks], st[kt][0]);
        st[kt][1] = MFMA16(kb[kt], qf[1][ks], st[kt][1]);
      }
    }
    __builtin_amdgcn_s_setprio(0);
    // p = exp2(s'), packed bf16 P into per-wave LDS
    #pragma unroll
    for (int mq = 0; mq < 2; ++mq) {
      const int prow = mq * 16 + lr;
      const int rs = (prow & 7) << 4;
      #pragma unroll
      for (int kt = 0; kt < 4; ++kt) {
        bf16x4 pk;
        pk[0] = (bf16_t)EXP2F(st[kt][mq][0]);
        pk[1] = (bf16_t)EXP2F(st[kt][mq][1]);
        pk[2] = (bf16_t)EXP2F(st[kt][mq][2]);
        pk[3] = (bf16_t)EXP2F(st[kt][mq][3]);
        *(bf16x4*)(psw + prow * 128 + ((kt * 32 + lg * 8) ^ rs)) = pk;
      }
    }
    // O += P V ; denom += P * ones (C/D layout matches acc_o rows)
    #pragma unroll
    for (int ks = 0; ks < 2; ++ks) {
      bf16x8 pa[2], vb[4];
      #pragma unroll
      for (int mt = 0; mt < 2; ++mt) {
        const int row = mt * 16 + lr;
        pa[mt] = *(const bf16x8*)(psw + row * 128 +
                                  ((ks * 64 + lg * 16) ^ ((row & 7) << 4)));
      }
      #pragma unroll
      for (int dt = 0; dt < 4; ++dt) {
        const int row = dt * 16 + lr;
        vb[dt] = *(const bf16x8*)((const char*)Vbuf + row * 128 +
                                  ((ks * 64 + lg * 16) ^ ((row & 7) << 4)));
      }
      __builtin_amdgcn_s_setprio(1);
      #pragma unroll
      for (int mt = 0; mt < 2; ++mt) {
        #pragma unroll
        for (int dt = 0; dt < 4; ++dt)
          acc_o[mt][dt] = MFMA16(pa[mt], vb[dt], acc_o[mt][dt]);
        acc_d[mt] = MFMA16(pa[mt], onesb, acc_d[mt]);
      }
      __builtin_amdgcn_s_setprio(0);
    }
  };

  // prologue: stage tile 0 fully
  bf16x8 va, vb;
  stageK(KsA, 0);
  loadV(0, va);
  writeV(VtA, va);

  for (int t = 0; t < 64; t += 2) {
    __syncthreads();  // publish stage(t): vmcnt+lgkm drained before barrier
    stageK(KsB, (t + 1) * 64);
    loadV((t + 1) * 64, vb);
    compute(KsA, VtA);
    writeV(VtB, vb);

    __syncthreads();  // publish stage(t+1)
    if (t + 2 < 64) {
      stageK(KsA, (t + 2) * 64);
      loadV((t + 2) * 64, va);
    }
    compute(KsB, VtB);
    if (t + 2 < 64) writeV(VtA, va);
  }

  // epilogue: normalize by acc_d, hi plane then lo plane via per-wave LDS
  // (Ps is wave-private: no barrier needed)
  #pragma unroll
  for (int mt = 0; mt < 2; ++mt) {
    #pragma unroll
    for (int r = 0; r < 4; ++r) {
      const float inv = 1.f / acc_d[mt][r];
      const int row = mt * 16 + 4 * lg + r;
      const int rsw = (row & 7) << 4;
      #pragma unroll
      for (int dt = 0; dt < 4; ++dt) {
        const float v = acc_o[mt][dt][r] * inv;
        acc_o[mt][dt][r] = v;
        const int col = dt * 16 + lr;
        *(bf16_t*)(psw + ((row * 128 + col * 2) ^ rsw)) = (bf16_t)v;
      }
    }
  }
  const int row2 = l & 31, hf = l >> 5;
  {
    bf16_t* orow = Oh + (size_t)(b * 4096 + q0 + row2) * 512 + h * 64 + hf * 32;
    #pragma unroll
    for (int c = 0; c < 4; ++c) {
      const bf16x8 vv =
          *(const bf16x8*)(psw + ((row2 * 128 + hf * 64 + c * 16) ^ ((row2 & 7) << 4)));
      *(bf16x8*)(orow + c * 8) = vv;
    }
  }
  #pragma unroll
  for (int mt = 0; mt < 2; ++mt) {
    #pragma unroll
    for (int r = 0; r < 4; ++r) {
      const int row = mt * 16 + 4 * lg + r;
      const int rsw = (row & 7) << 4;
      #pragma unroll
      for (int dt = 0; dt < 4; ++dt) {
        const float v = acc_o[mt][dt][r];
        const bf16_t hi = (bf16_t)v;
        const bf16_t lo = (bf16_t)(v - (float)hi);
        const int col = dt * 16 + lr;
        *(bf16_t*)(psw + ((row * 128 + col * 2) ^ rsw)) = lo;
      }
    }
  }
  {
    bf16_t* orow = Ol + (size_t)(b * 4096 + q0 + row2) * 512 + h * 64 + hf * 32;
    #pragma unroll
    for (int c = 0; c < 4; ++c) {
      const bf16x8 vv =
          *(const bf16x8*)(psw + ((row2 * 128 + hf * 64 + c * 16) ^ ((row2 & 7) << 4)));
      *(bf16x8*)(orow + c * 8) = vv;
    }
  }
}

// ------------------------------------------------------------- proj GEMM
__global__ __launch_bounds__(256) void gemm_proj(const bf16_t* __restrict__ Oh,
                                                 const bf16_t* __restrict__ Ol,
                                                 const bf16_t* __restrict__ Wph,
                                                 const bf16_t* __restrict__ Wpl,
                                                 const float* __restrict__ bproj,
                                                 float* __restrict__ Y) {
  extern __shared__ char smem[];
  char* const Ah = smem;
  char* const Al = smem + 16384;
  char* const Bh = smem + 32768;
  char* const Bl = smem + 49152;
  const int pos0 = blockIdx.y * 128;
  const int oc0 = blockIdx.x * 128;
  const int tid = threadIdx.x;
  const int l = tid & 63, w = tid >> 6;
  const int wr = w >> 1, wc = w & 1;
  f32x4 acc[4][4] = {};
  for (int kt = 0; kt < 512; kt += 64) {
    __syncthreads();
    #pragma unroll
    for (int i = 0; i < 4; ++i) {
      const int chunk = tid + 256 * i;
      const int row = chunk >> 3;
      const int cp = (chunk & 7) ^ (row & 7);  // pre-swizzled source
      const size_t offA = (size_t)(pos0 + row) * 512 + kt + cp * 8;
      const size_t offB = (size_t)(oc0 + row) * 512 + kt + cp * 8;
      __builtin_amdgcn_global_load_lds(
          (const __attribute__((address_space(1))) void*)(Oh + offA),
          (__attribute__((address_space(3))) void*)(Ah + chunk * 16), 16, 0, 0);
      __builtin_amdgcn_global_load_lds(
          (const __attribute__((address_space(1))) void*)(Ol + offA),
          (__attribute__((address_space(3))) void*)(Al + chunk * 16), 16, 0, 0);
      __builtin_amdgcn_global_load_lds(
          (const __attribute__((address_space(1))) void*)(Wph + offB),
          (__attribute__((address_space(3))) void*)(Bh + chunk * 16), 16, 0, 0);
      __builtin_amdgcn_global_load_lds(
          (const __attribute__((address_space(1))) void*)(Wpl + offB),
          (__attribute__((address_space(3))) void*)(Bl + chunk * 16), 16, 0, 0);
    }
    __syncthreads();
    #pragma unroll
    for (int ks = 0; ks < 2; ++ks) {
      bf16x8 ah[4], al[4], bh[4], bl[4];
      #pragma unroll
      for (int mt = 0; mt < 4; ++mt) {
        const int row = wr * 64 + mt * 16 + (l & 15);
        const int off = row * 128 + ((ks * 64 + (l >> 4) * 16) ^ ((row & 7) << 4));
        ah[mt] = *(const bf16x8*)(Ah + off);
        al[mt] = *(const bf16x8*)(Al + off);
      }
      #pragma unroll
      for (int nt = 0; nt < 4; ++nt) {
        const int row = wc * 64 + nt * 16 + (l & 15);
        const int off = row * 128 + ((ks * 64 + (l >> 4) * 16) ^ ((row & 7) << 4));
        bh[nt] = *(const bf16x8*)(Bh + off);
        bl[nt] = *(const bf16x8*)(Bl + off);
      }
      #pragma unroll
      for (int mt = 0; mt < 4; ++mt)
        #pragma unroll
        for (int nt = 0; nt < 4; ++nt) {
          acc[mt][nt] = MFMA16(ah[mt], bh[nt], acc[mt][nt]);
          acc[mt][nt] = MFMA16(ah[mt], bl[nt], acc[mt][nt]);
          acc[mt][nt] = MFMA16(al[mt], bh[nt], acc[mt][nt]);
        }
    }
  }
  #pragma unroll
  for (int mt = 0; mt < 4; ++mt) {
    const int posb = pos0 + wr * 64 + mt * 16 + 4 * (l >> 4);
    const int bb_ = posb >> 12, p = posb & 4095;
    #pragma unroll
    for (int nt = 0; nt < 4; ++nt) {
      const int oc = oc0 + wc * 64 + nt * 16 + (l & 15);
      const float bias = bproj[oc];
      float4 v;
      v.x = acc[mt][nt][0] + bias;
      v.y = acc[mt][nt][1] + bias;
      v.z = acc[mt][nt][2] + bias;
      v.w = acc[mt][nt][3] + bias;
      *(float4*)(Y + ((size_t)(bb_ * 512 + oc)) * 4096 + p) = v;
    }
  }
}

// ------------------------------------------------------------- launch
extern "C" void kernel_launch(void* const* d_in, const int* in_sizes, int n_in,
                              void* d_out, int out_size, void* d_ws, size_t ws_size,
                              hipStream_t stream) {
  const float* X = (const float*)d_in[0];
  const float* gamma = (const float*)d_in[1];
  const float* beta = (const float*)d_in[2];
  const float* Wqkv = (const float*)d_in[3];
  const float* bqkv = (const float*)d_in[4];
  const float* Wproj = (const float*)d_in[5];
  const float* bproj = (const float*)d_in[6];
  float* Y = (float*)d_out;
  char* ws = (char*)d_ws;

  bf16_t* Wq_hi = (bf16_t*)(ws + 0);
  bf16_t* Wq_lo = (bf16_t*)(ws + 1572864);
  bf16_t* Wp_hi = (bf16_t*)(ws + 3145728);
  bf16_t* Wp_lo = (bf16_t*)(ws + 3670016);
  bf16_t* T_hi = (bf16_t*)(ws + 4194304);
  bf16_t* T_lo = (bf16_t*)(ws + 20971520);
  bf16_t* QKVb = (bf16_t*)(ws + 37748736);
  bf16_t* O_hi = T_hi;  // alias: T dead after gemm_qkv
  bf16_t* O_lo = T_lo;

  cvt_kernel<<<1024, 256, 0, stream>>>(Wqkv, Wproj, Wq_hi, Wq_lo, Wp_hi, Wp_lo);
  ln_kernel<<<dim3(128, 4), 256, 0, stream>>>(X, gamma, beta, T_hi, T_lo);
  gemm_qkv<<<dim3(128, 12), 256, 65536, stream>>>(Wq_hi, Wq_lo, T_hi, T_lo, bqkv, QKVb);
  attn_kernel<<<dim3(512), 512, 0, stream>>>(QKVb, O_hi, O_lo);
  gemm_proj<<<dim3(4, 128), 256, 65536, stream>>>(O_hi, O_lo, Wp_hi, Wp_lo, bproj, Y);
}